// Round 1
// baseline (3248.736 us; speedup 1.0000x reference)
//
#include <hip/hip_runtime.h>

#define TT 32
#define RES_C 128
#define SKIP_C 128
#define TFULL 8192
#define NB 40
#define BATCH 4
#define SKIP_SZ 4096

#define F4C(p) (*(const float4*)(p))

// One WaveNet block: dilated causal conv (k=2) -> tanh*sigmoid gate ->
// 1x1 res conv (+bias, +residual) and 1x1 skip conv (+bias).
// Activations are right-aligned in [B][128][8192] buffers: output columns
// [col0, 8192). Output col c uses input cols c-d (tap0) and c (tap1);
// residual adds input col c at the same channel.
__global__ __launch_bounds__(256) void wavenet_block(
    const float* __restrict__ in, float* __restrict__ outb,
    const float* __restrict__ Wd,   // [128][128][2]
    const float* __restrict__ Wr,   // [128][128]
    const float* __restrict__ br,   // [128]
    const float* __restrict__ Ws,   // [128][128]
    const float* __restrict__ bs,   // [128]
    float* __restrict__ skip,       // [B][128][4096] for this block
    int d, int col0)
{
    __shared__ float xA[RES_C][TT];   // in[ch][col-d]
    __shared__ float xB[RES_C][TT];   // in[ch][col]
    __shared__ float gl[RES_C][TT];   // gated

    const int b = blockIdx.y;
    const int tile0 = col0 + blockIdx.x * TT;
    const int nt = min(TT, TFULL - tile0);   // valid cols in this tile (>=1)
    const int tid = threadIdx.x;
    const float* inb = in + (size_t)b * RES_C * TFULL;

    // Stage input tiles (coalesced scalar loads; zero-fill tail so the
    // GEMMs below compute zeros there, discarded on store).
    for (int idx = tid; idx < RES_C * TT; idx += 256) {
        int r = idx >> 5;       // TT == 32
        int c = idx & 31;
        float va = 0.f, vb = 0.f;
        if (c < nt) {
            va = inb[r * TFULL + (tile0 - d) + c];
            vb = inb[r * TFULL + tile0 + c];
        }
        xA[r][c] = va;
        xB[r][c] = vb;
    }
    __syncthreads();

    const int tg = tid & 7;     // t-group: t = tg*4 .. tg*4+3
    const int og = tid >> 3;    // o-group: o = og*4 .. og*4+3
    const int o0 = og * 4;
    const int t0 = tg * 4;

    // ---- Phase 1: dilated conv GEMM y[o,t] = sum_i W0[o,i]*xA[i,t] + W1[o,i]*xB[i,t]
    float acc[4][4];
#pragma unroll
    for (int oo = 0; oo < 4; ++oo)
#pragma unroll
        for (int tt = 0; tt < 4; ++tt) acc[oo][tt] = 0.f;

    for (int i = 0; i < 128; i += 2) {
        float4 wv[4];
#pragma unroll
        for (int oo = 0; oo < 4; ++oo)
            wv[oo] = F4C(Wd + (size_t)(o0 + oo) * 256 + i * 2);  // {w0[i],w1[i],w0[i+1],w1[i+1]}
        float xa0[4], xb0[4], xa1[4], xb1[4];
        *(float4*)xa0 = F4C(&xA[i][t0]);
        *(float4*)xb0 = F4C(&xB[i][t0]);
        *(float4*)xa1 = F4C(&xA[i + 1][t0]);
        *(float4*)xb1 = F4C(&xB[i + 1][t0]);
#pragma unroll
        for (int oo = 0; oo < 4; ++oo) {
            const float w0 = wv[oo].x, w1 = wv[oo].y, w2 = wv[oo].z, w3 = wv[oo].w;
#pragma unroll
            for (int tt = 0; tt < 4; ++tt) {
                acc[oo][tt] = fmaf(w0, xa0[tt], acc[oo][tt]);
                acc[oo][tt] = fmaf(w1, xb0[tt], acc[oo][tt]);
                acc[oo][tt] = fmaf(w2, xa1[tt], acc[oo][tt]);
                acc[oo][tt] = fmaf(w3, xb1[tt], acc[oo][tt]);
            }
        }
    }

    // ---- Phase 2: gated activation, write to LDS
#pragma unroll
    for (int oo = 0; oo < 4; ++oo) {
#pragma unroll
        for (int tt = 0; tt < 4; ++tt) {
            float y = acc[oo][tt];
            float th = tanhf(y);
            float sg = 1.f / (1.f + expf(-y));
            acc[oo][tt] = th * sg;
        }
        *(float4*)&gl[o0 + oo][t0] = make_float4(acc[oo][0], acc[oo][1], acc[oo][2], acc[oo][3]);
    }
    __syncthreads();

    // ---- Phase 3: res & skip 1x1 GEMMs over gated
    float accr[4][4], accs[4][4];
#pragma unroll
    for (int oo = 0; oo < 4; ++oo)
#pragma unroll
        for (int tt = 0; tt < 4; ++tt) { accr[oo][tt] = 0.f; accs[oo][tt] = 0.f; }

    for (int i = 0; i < 128; i += 4) {
        float4 wrv[4], wsv[4];
#pragma unroll
        for (int oo = 0; oo < 4; ++oo) {
            wrv[oo] = F4C(Wr + (size_t)(o0 + oo) * 128 + i);
            wsv[oo] = F4C(Ws + (size_t)(o0 + oo) * 128 + i);
        }
        float gv[4][4];   // [j][tt]
#pragma unroll
        for (int j = 0; j < 4; ++j)
            *(float4*)gv[j] = F4C(&gl[i + j][t0]);
#pragma unroll
        for (int oo = 0; oo < 4; ++oo) {
            const float r0 = wrv[oo].x, r1 = wrv[oo].y, r2 = wrv[oo].z, r3 = wrv[oo].w;
            const float s0 = wsv[oo].x, s1 = wsv[oo].y, s2 = wsv[oo].z, s3 = wsv[oo].w;
#pragma unroll
            for (int tt = 0; tt < 4; ++tt) {
                accr[oo][tt] = fmaf(r0, gv[0][tt], accr[oo][tt]);
                accr[oo][tt] = fmaf(r1, gv[1][tt], accr[oo][tt]);
                accr[oo][tt] = fmaf(r2, gv[2][tt], accr[oo][tt]);
                accr[oo][tt] = fmaf(r3, gv[3][tt], accr[oo][tt]);
                accs[oo][tt] = fmaf(s0, gv[0][tt], accs[oo][tt]);
                accs[oo][tt] = fmaf(s1, gv[1][tt], accs[oo][tt]);
                accs[oo][tt] = fmaf(s2, gv[2][tt], accs[oo][tt]);
                accs[oo][tt] = fmaf(s3, gv[3][tt], accs[oo][tt]);
            }
        }
    }

    // ---- Phase 4: epilogue (bias, residual add, stores)
#pragma unroll
    for (int oo = 0; oo < 4; ++oo) {
        const int o = o0 + oo;
        const float rb = br[o];
        const float sb = bs[o];
#pragma unroll
        for (int tt = 0; tt < 4; ++tt) {
            const int t = t0 + tt;
            if (t < nt) {
                const int col = tile0 + t;
                const float resv = accr[oo][tt] + rb + xB[o][t];
                outb[(size_t)(b * RES_C + o) * TFULL + col] = resv;
                if (col >= TFULL - SKIP_SZ) {
                    skip[(size_t)(b * SKIP_C + o) * SKIP_SZ + (col - (TFULL - SKIP_SZ))] =
                        accs[oo][tt] + sb;
                }
            }
        }
    }
}

extern "C" void kernel_launch(void* const* d_in, const int* in_sizes, int n_in,
                              void* d_out, int out_size, void* d_ws, size_t ws_size,
                              hipStream_t stream) {
    const float* x  = (const float*)d_in[0];
    const float* Wd = (const float*)d_in[1];
    const float* Wr = (const float*)d_in[2];
    const float* br = (const float*)d_in[3];
    const float* Ws = (const float*)d_in[4];
    const float* bs = (const float*)d_in[5];
    float* out = (float*)d_out;

    float* bufA = (float*)d_ws;
    float* bufB = bufA + (size_t)BATCH * RES_C * TFULL;

    int L = TFULL;
    const float* cur = x;   // first block reads the input directly
    for (int i = 0; i < NB; ++i) {
        const int d = 1 << (i % 10);
        const int Lout = L - d;
        const int col0 = TFULL - Lout;
        float* nxt = (i & 1) ? bufB : bufA;
        const int tiles = (Lout + TT - 1) / TT;
        dim3 grid(tiles, BATCH);
        wavenet_block<<<grid, dim3(256), 0, stream>>>(
            cur, nxt,
            Wd + (size_t)i * RES_C * RES_C * 2,
            Wr + (size_t)i * RES_C * RES_C,
            br + (size_t)i * RES_C,
            Ws + (size_t)i * RES_C * RES_C,
            bs + (size_t)i * RES_C,
            out + (size_t)i * BATCH * SKIP_C * SKIP_SZ,
            d, col0);
        cur = nxt;
        L = Lout;
    }
}

// Round 2
// 1312.820 us; speedup vs baseline: 2.4746x; 2.4746x over previous
//
#include <hip/hip_runtime.h>

typedef __attribute__((ext_vector_type(8))) short bf16x8;
typedef __attribute__((ext_vector_type(4))) short bf16x4;
typedef __attribute__((ext_vector_type(4))) float f32x4;

#define TFULL 8192
#define RC 128
#define NB 40
#define BATCH 4
#define SKIP_SZ 4096

__device__ __forceinline__ unsigned short f2bf(float f) {
    unsigned u = __builtin_bit_cast(unsigned, f);
    u += 0x7FFFu + ((u >> 16) & 1u);          // round-to-nearest-even
    return (unsigned short)(u >> 16);
}
__device__ __forceinline__ float bf2f(unsigned short h) {
    unsigned u = ((unsigned)h) << 16;
    return __builtin_bit_cast(float, u);
}

// ---------------------------------------------------------------------------
// Pre-pass 1: transpose x [B][128ch][8192col] fp32 -> hi/lo bf16 [B][col][ch]
// ---------------------------------------------------------------------------
__global__ __launch_bounds__(256) void xpose_split(
    const float* __restrict__ x,
    unsigned short* __restrict__ Xh, unsigned short* __restrict__ Xl)
{
    __shared__ float t[32][65];
    const int col0 = blockIdx.x * 64;
    const int ch0  = blockIdx.y * 32;
    const int b    = blockIdx.z;
    const int tid  = threadIdx.x;
    const int tx = tid & 63, ty = tid >> 6;
#pragma unroll
    for (int i = 0; i < 8; ++i) {
        int ch = ty + i * 4;
        t[ch][tx] = x[((size_t)(b * RC + ch0 + ch)) * TFULL + col0 + tx];
    }
    __syncthreads();
    for (int idx = tid; idx < 64 * 32; idx += 256) {
        int col = idx >> 5, ch = idx & 31;
        float v = t[ch][col];
        unsigned short h = f2bf(v);
        unsigned short l = f2bf(v - bf2f(h));
        size_t off = ((size_t)(b * TFULL + col0 + col)) * RC + ch0 + ch;
        Xh[off] = h;
        Xl[off] = l;
    }
}

// ---------------------------------------------------------------------------
// Pre-pass 2: pack weights into per-MFMA-A-fragment layout, hi/lo bf16.
// Fragment element: A[m][k], lane l holds rows m=16*mf+(l&15),
// k = 32*ks + (l>>4)*8 + j (j=0..7 contiguous). Dilated k = tap*128 + i.
// Dst flat: ((blk*KS*8 + ks*8 + mf)*64 + lane)*8 + j.
// ---------------------------------------------------------------------------
__global__ __launch_bounds__(256) void wpack(
    const float* __restrict__ Wd, const float* __restrict__ Wr, const float* __restrict__ Ws,
    unsigned short* __restrict__ Wdh, unsigned short* __restrict__ Wdl,
    unsigned short* __restrict__ Wrh, unsigned short* __restrict__ Wrl,
    unsigned short* __restrict__ Wsh, unsigned short* __restrict__ Wsl)
{
    const int Nd = NB * 4096;   // 8ks * 8mf * 64lane per block
    const int Nr = NB * 2048;   // 4ks * 8mf * 64lane per block
    int id = blockIdx.x * 256 + threadIdx.x;
    const float* src;
    unsigned short *dh, *dl;
    int blk, rloc;
    bool dil = false;
    size_t dbase;
    if (id < Nd)               { dil = true; blk = id >> 12; rloc = id & 4095; dh = Wdh; dl = Wdl; src = Wd; dbase = (size_t)id * 8; }
    else if (id < Nd + Nr)     { int t = id - Nd;      blk = t >> 11; rloc = t & 2047; dh = Wrh; dl = Wrl; src = Wr; dbase = (size_t)t * 8; }
    else if (id < Nd + 2 * Nr) { int t = id - Nd - Nr; blk = t >> 11; rloc = t & 2047; dh = Wsh; dl = Wsl; src = Ws; dbase = (size_t)t * 8; }
    else return;
    const int ks = rloc >> 9, mf = (rloc >> 6) & 7, lane = rloc & 63;
    const int m = mf * 16 + (lane & 15);
    const int kb = ks * 32 + ((lane >> 4) << 3);
    bf16x8 hv, lv;
#pragma unroll
    for (int j = 0; j < 8; ++j) {
        int k = kb + j;
        float w;
        if (dil) {
            int tap = k >> 7, i = k & 127;
            w = src[((((size_t)blk * 128 + m) * 128) + i) * 2 + tap];
        } else {
            w = src[(((size_t)blk * 128 + m) * 128) + k];
        }
        unsigned short h = f2bf(w);
        hv[j] = (short)h;
        lv[j] = (short)f2bf(w - bf2f(h));
    }
    *(bf16x8*)(dh + dbase) = hv;
    *(bf16x8*)(dl + dbase) = lv;
}

// ---------------------------------------------------------------------------
// One WaveNet block. Stream layout [B][col][ch], right-aligned (valid cols
// [col0,8192)), stored as hi/lo bf16 pair. Output col c reads input cols
// c-d (tap0) and c (tap1); residual adds input col c.
// WG = 256 thr = 4 waves; tile = 128 out-ch x 32 cols; wave = 32ch x 32col.
// All GEMMs via mfma_f32_16x16x32_bf16 with 3-product hi/lo splitting.
// ---------------------------------------------------------------------------
__global__ __launch_bounds__(256) void wn_block(
    const unsigned short* __restrict__ Xh, const unsigned short* __restrict__ Xl,
    unsigned short* __restrict__ Yh, unsigned short* __restrict__ Yl,
    const unsigned short* __restrict__ Wdh, const unsigned short* __restrict__ Wdl,
    const unsigned short* __restrict__ Wrh, const unsigned short* __restrict__ Wrl,
    const unsigned short* __restrict__ Wsh, const unsigned short* __restrict__ Wsl,
    const float* __restrict__ br, const float* __restrict__ bs,
    float* __restrict__ skip, int d, int col0)
{
    __shared__ short glds[2][32 * 128];   // gated hi/lo, XOR-swizzled

    const int b     = blockIdx.y;
    const int tile0 = col0 + blockIdx.x * 32;
    const int tid   = threadIdx.x;
    const int lane  = tid & 63;
    const int wave  = tid >> 6;          // 0..3 -> m0
    const int m0    = wave * 32;
    const int l15   = lane & 15, lq = lane >> 4;
    const size_t xbase = (size_t)b * TFULL * RC;

    f32x4 acc[2][2];
#pragma unroll
    for (int mf = 0; mf < 2; ++mf)
#pragma unroll
        for (int nf = 0; nf < 2; ++nf) acc[mf][nf] = (f32x4){0.f, 0.f, 0.f, 0.f};

    // ---- dilated conv GEMM: K = 256 (tap-major: k = tap*128 + ch)
#pragma unroll
    for (int ks = 0; ks < 8; ++ks) {
        const int tap = ks >> 2;
        const int chb = (ks & 3) * 32 + lq * 8;
        bf16x8 ah[2], al[2];
#pragma unroll
        for (int mf = 0; mf < 2; ++mf) {
            size_t wi = ((size_t)(ks * 8 + wave * 2 + mf) * 64 + lane) * 8;
            ah[mf] = *(const bf16x8*)(Wdh + wi);
            al[mf] = *(const bf16x8*)(Wdl + wi);
        }
        bf16x8 bh[2], bl[2];
#pragma unroll
        for (int nf = 0; nf < 2; ++nf) {
            int c = tile0 + nf * 16 + l15;
            c = c > TFULL - 1 ? TFULL - 1 : c;   // clamp tail (masked at store)
            if (tap == 0) c -= d;
            size_t off = xbase + (size_t)c * RC + chb;
            bh[nf] = *(const bf16x8*)(Xh + off);
            bl[nf] = *(const bf16x8*)(Xl + off);
        }
#pragma unroll
        for (int mf = 0; mf < 2; ++mf)
#pragma unroll
            for (int nf = 0; nf < 2; ++nf) {
                acc[mf][nf] = __builtin_amdgcn_mfma_f32_16x16x32_bf16(ah[mf], bh[nf], acc[mf][nf], 0, 0, 0);
                acc[mf][nf] = __builtin_amdgcn_mfma_f32_16x16x32_bf16(ah[mf], bl[nf], acc[mf][nf], 0, 0, 0);
                acc[mf][nf] = __builtin_amdgcn_mfma_f32_16x16x32_bf16(al[mf], bh[nf], acc[mf][nf], 0, 0, 0);
            }
    }

    // ---- gate + write gated hi/lo to LDS (swizzled [col][ch])
#pragma unroll
    for (int mf = 0; mf < 2; ++mf)
#pragma unroll
        for (int nf = 0; nf < 2; ++nf) {
            const int n   = nf * 16 + l15;
            const int ch0 = m0 + mf * 16 + lq * 4;
            const unsigned byteoff = (unsigned)((n * 256 + ch0 * 2) ^ ((n & 7) << 4));
            bf16x4 hv, lv;
#pragma unroll
            for (int r = 0; r < 4; ++r) {
                float y = acc[mf][nf][r];
                float g = tanhf(y) * (1.f / (1.f + expf(-y)));
                unsigned short h = f2bf(g);
                hv[r] = (short)h;
                lv[r] = (short)f2bf(g - bf2f(h));
            }
            *(bf16x4*)((char*)glds[0] + byteoff) = hv;
            *(bf16x4*)((char*)glds[1] + byteoff) = lv;
        }
    __syncthreads();

    // ---- res & skip 1x1 GEMMs: K = 128 over gated
    f32x4 accr[2][2], accs[2][2];
#pragma unroll
    for (int mf = 0; mf < 2; ++mf)
#pragma unroll
        for (int nf = 0; nf < 2; ++nf) {
            accr[mf][nf] = (f32x4){0.f, 0.f, 0.f, 0.f};
            accs[mf][nf] = (f32x4){0.f, 0.f, 0.f, 0.f};
        }
#pragma unroll
    for (int ks = 0; ks < 4; ++ks) {
        const int chb = ks * 32 + lq * 8;
        bf16x8 rh[2], rl[2], sh[2], sl[2];
#pragma unroll
        for (int mf = 0; mf < 2; ++mf) {
            size_t wi = ((size_t)(ks * 8 + wave * 2 + mf) * 64 + lane) * 8;
            rh[mf] = *(const bf16x8*)(Wrh + wi);
            rl[mf] = *(const bf16x8*)(Wrl + wi);
            sh[mf] = *(const bf16x8*)(Wsh + wi);
            sl[mf] = *(const bf16x8*)(Wsl + wi);
        }
        bf16x8 gh[2], gl[2];
#pragma unroll
        for (int nf = 0; nf < 2; ++nf) {
            const int n = nf * 16 + l15;
            const unsigned byteoff = (unsigned)((n * 256 + chb * 2) ^ ((n & 7) << 4));
            gh[nf] = *(const bf16x8*)((char*)glds[0] + byteoff);
            gl[nf] = *(const bf16x8*)((char*)glds[1] + byteoff);
        }
#pragma unroll
        for (int mf = 0; mf < 2; ++mf)
#pragma unroll
            for (int nf = 0; nf < 2; ++nf) {
                accr[mf][nf] = __builtin_amdgcn_mfma_f32_16x16x32_bf16(rh[mf], gh[nf], accr[mf][nf], 0, 0, 0);
                accr[mf][nf] = __builtin_amdgcn_mfma_f32_16x16x32_bf16(rh[mf], gl[nf], accr[mf][nf], 0, 0, 0);
                accr[mf][nf] = __builtin_amdgcn_mfma_f32_16x16x32_bf16(rl[mf], gh[nf], accr[mf][nf], 0, 0, 0);
                accs[mf][nf] = __builtin_amdgcn_mfma_f32_16x16x32_bf16(sh[mf], gh[nf], accs[mf][nf], 0, 0, 0);
                accs[mf][nf] = __builtin_amdgcn_mfma_f32_16x16x32_bf16(sh[mf], gl[nf], accs[mf][nf], 0, 0, 0);
                accs[mf][nf] = __builtin_amdgcn_mfma_f32_16x16x32_bf16(sl[mf], gh[nf], accs[mf][nf], 0, 0, 0);
            }
    }

    // ---- epilogue: residual add (fp32), re-split stream, skip store
    const int nt = TFULL - tile0 < 32 ? TFULL - tile0 : 32;
#pragma unroll
    for (int mf = 0; mf < 2; ++mf)
#pragma unroll
        for (int nf = 0; nf < 2; ++nf) {
            const int n   = nf * 16 + l15;
            const int c   = tile0 + n;
            const int cc  = c > TFULL - 1 ? TFULL - 1 : c;
            const int ch0 = m0 + mf * 16 + lq * 4;
            const size_t off = xbase + (size_t)cc * RC + ch0;
            bf16x4 ih = *(const bf16x4*)(Xh + off);
            bf16x4 il = *(const bf16x4*)(Xl + off);
            const float4 brv = *(const float4*)(br + ch0);
            const float4 bsv = *(const float4*)(bs + ch0);
            bf16x4 oh, ol;
            float sk[4];
#pragma unroll
            for (int r = 0; r < 4; ++r) {
                float inv = bf2f((unsigned short)ih[r]) + bf2f((unsigned short)il[r]);
                float rv = accr[mf][nf][r] + ((const float*)&brv)[r] + inv;
                unsigned short h = f2bf(rv);
                oh[r] = (short)h;
                ol[r] = (short)f2bf(rv - bf2f(h));
                sk[r] = accs[mf][nf][r] + ((const float*)&bsv)[r];
            }
            if (n < nt) {
                *(bf16x4*)(Yh + off) = oh;
                *(bf16x4*)(Yl + off) = ol;
                if (c >= TFULL - SKIP_SZ) {
                    float* sp = skip + ((size_t)b * RC + ch0) * SKIP_SZ + (c - (TFULL - SKIP_SZ));
#pragma unroll
                    for (int r = 0; r < 4; ++r) sp[(size_t)r * SKIP_SZ] = sk[r];
                }
            }
        }
}

extern "C" void kernel_launch(void* const* d_in, const int* in_sizes, int n_in,
                              void* d_out, int out_size, void* d_ws, size_t ws_size,
                              hipStream_t stream) {
    const float* x  = (const float*)d_in[0];
    const float* Wd = (const float*)d_in[1];
    const float* Wr = (const float*)d_in[2];
    const float* br = (const float*)d_in[3];
    const float* Ws = (const float*)d_in[4];
    const float* bs = (const float*)d_in[5];
    float* out = (float*)d_out;

    // ws layout (elems of u16): 4 stream slots, then packed weights hi/lo
    const size_t SLOT = (size_t)BATCH * TFULL * RC;       // 4.19M elems
    unsigned short* Xs0h = (unsigned short*)d_ws;
    unsigned short* Xs0l = Xs0h + SLOT;
    unsigned short* Xs1h = Xs0l + SLOT;
    unsigned short* Xs1l = Xs1h + SLOT;
    unsigned short* Wdh = Xs1l + SLOT;
    unsigned short* Wdl = Wdh + (size_t)NB * 32768;
    unsigned short* Wrh = Wdl + (size_t)NB * 32768;
    unsigned short* Wrl = Wrh + (size_t)NB * 16384;
    unsigned short* Wsh = Wrl + (size_t)NB * 16384;
    unsigned short* Wsl = Wsh + (size_t)NB * 16384;

    xpose_split<<<dim3(TFULL / 64, RC / 32, BATCH), 256, 0, stream>>>(x, Xs0h, Xs0l);
    {
        int total = NB * 4096 + 2 * NB * 2048;
        wpack<<<dim3((total + 255) / 256), 256, 0, stream>>>(Wd, Wr, Ws, Wdh, Wdl, Wrh, Wrl, Wsh, Wsl);
    }

    int L = TFULL;
    int pp = 0;
    for (int i = 0; i < NB; ++i) {
        const int d = 1 << (i % 10);
        const int Lout = L - d;
        const int col0 = TFULL - Lout;
        const int tiles = (Lout + 31) / 32;
        unsigned short* curh = pp ? Xs1h : Xs0h;
        unsigned short* curl = pp ? Xs1l : Xs0l;
        unsigned short* nxth = pp ? Xs0h : Xs1h;
        unsigned short* nxtl = pp ? Xs0l : Xs1l;
        wn_block<<<dim3(tiles, BATCH), 256, 0, stream>>>(
            curh, curl, nxth, nxtl,
            Wdh + (size_t)i * 32768, Wdl + (size_t)i * 32768,
            Wrh + (size_t)i * 16384, Wrl + (size_t)i * 16384,
            Wsh + (size_t)i * 16384, Wsl + (size_t)i * 16384,
            br + (size_t)i * RC, bs + (size_t)i * RC,
            out + (size_t)i * BATCH * RC * SKIP_SZ, d, col0);
        pp ^= 1;
        L = Lout;
    }
}

// Round 3
// 1166.093 us; speedup vs baseline: 2.7860x; 1.1258x over previous
//
#include <hip/hip_runtime.h>

typedef __attribute__((ext_vector_type(8))) short bf16x8;
typedef __attribute__((ext_vector_type(4))) short bf16x4;
typedef __attribute__((ext_vector_type(4))) float f32x4;

#define TFULL 8192
#define RC 128
#define NB 40
#define BATCH 4
#define SKIP_SZ 4096

// LDS byte layout per WG (padded col pitch 272 = 256 data + 16 pad -> all
// ds_read_b128 / ds_write_b128 provably bank-conflict-free: slot stride 17).
//   tensors 0..3: staged X  [hl][tap][32 col][272 B]
//   tensors 4..5: gated     [hl]     [32 col][272 B]
#define COLPITCH 272
#define TSZ (32 * COLPITCH)
#define GATED_BASE (4 * TSZ)
#define LDS_BYTES (6 * TSZ)

__device__ __forceinline__ unsigned short f2bf(float f) {
    unsigned u = __builtin_bit_cast(unsigned, f);
    u += 0x7FFFu + ((u >> 16) & 1u);          // round-to-nearest-even
    return (unsigned short)(u >> 16);
}
__device__ __forceinline__ float bf2f(unsigned short h) {
    unsigned u = ((unsigned)h) << 16;
    return __builtin_bit_cast(float, u);
}

// ---------------------------------------------------------------------------
// Pre-pass 1: transpose x [B][128ch][8192col] fp32 -> hi/lo bf16 [B][col][ch]
// ---------------------------------------------------------------------------
__global__ __launch_bounds__(256) void xpose_split(
    const float* __restrict__ x,
    unsigned short* __restrict__ Xh, unsigned short* __restrict__ Xl)
{
    __shared__ float t[32][65];
    const int col0 = blockIdx.x * 64;
    const int ch0  = blockIdx.y * 32;
    const int b    = blockIdx.z;
    const int tid  = threadIdx.x;
    const int tx = tid & 63, ty = tid >> 6;
#pragma unroll
    for (int i = 0; i < 8; ++i) {
        int ch = ty + i * 4;
        t[ch][tx] = x[((size_t)(b * RC + ch0 + ch)) * TFULL + col0 + tx];
    }
    __syncthreads();
    for (int idx = tid; idx < 64 * 32; idx += 256) {
        int col = idx >> 5, ch = idx & 31;
        float v = t[ch][col];
        unsigned short h = f2bf(v);
        unsigned short l = f2bf(v - bf2f(h));
        size_t off = ((size_t)(b * TFULL + col0 + col)) * RC + ch0 + ch;
        Xh[off] = h;
        Xl[off] = l;
    }
}

// ---------------------------------------------------------------------------
// Pre-pass 2: pack weights into per-MFMA-A-fragment layout, hi/lo bf16.
// A[m][k]: lane l holds rows m=16*mf+(l&15), k = 32*ks + (l>>4)*8 + j.
// Dilated k = tap*128 + i. Dst flat: ((blk*KS*8 + ks*8 + mf)*64 + lane)*8 + j.
// ---------------------------------------------------------------------------
__global__ __launch_bounds__(256) void wpack(
    const float* __restrict__ Wd, const float* __restrict__ Wr, const float* __restrict__ Ws,
    unsigned short* __restrict__ Wdh, unsigned short* __restrict__ Wdl,
    unsigned short* __restrict__ Wrh, unsigned short* __restrict__ Wrl,
    unsigned short* __restrict__ Wsh, unsigned short* __restrict__ Wsl)
{
    const int Nd = NB * 4096;   // 8ks * 8mf * 64lane per block
    const int Nr = NB * 2048;   // 4ks * 8mf * 64lane per block
    int id = blockIdx.x * 256 + threadIdx.x;
    const float* src;
    unsigned short *dh, *dl;
    int blk, rloc;
    bool dil = false;
    size_t dbase;
    if (id < Nd)               { dil = true; blk = id >> 12; rloc = id & 4095; dh = Wdh; dl = Wdl; src = Wd; dbase = (size_t)id * 8; }
    else if (id < Nd + Nr)     { int t = id - Nd;      blk = t >> 11; rloc = t & 2047; dh = Wrh; dl = Wrl; src = Wr; dbase = (size_t)t * 8; }
    else if (id < Nd + 2 * Nr) { int t = id - Nd - Nr; blk = t >> 11; rloc = t & 2047; dh = Wsh; dl = Wsl; src = Ws; dbase = (size_t)t * 8; }
    else return;
    const int ks = rloc >> 9, mf = (rloc >> 6) & 7, lane = rloc & 63;
    const int m = mf * 16 + (lane & 15);
    const int kb = ks * 32 + ((lane >> 4) << 3);
    bf16x8 hv, lv;
#pragma unroll
    for (int j = 0; j < 8; ++j) {
        int k = kb + j;
        float w;
        if (dil) {
            int tap = k >> 7, i = k & 127;
            w = src[((((size_t)blk * 128 + m) * 128) + i) * 2 + tap];
        } else {
            w = src[(((size_t)blk * 128 + m) * 128) + k];
        }
        unsigned short h = f2bf(w);
        hv[j] = (short)h;
        lv[j] = (short)f2bf(w - bf2f(h));
    }
    *(bf16x8*)(dh + dbase) = hv;
    *(bf16x8*)(dl + dbase) = lv;
}

// ---------------------------------------------------------------------------
// One WaveNet block. Stream [B][col][ch] hi/lo bf16, right-aligned.
// WG = 256 thr = 4 waves; tile = 128 out-ch x 32 cols; wave = 32ch x 32col.
// X tiles (both taps, hi+lo) reg-staged into padded LDS once, then all
// GEMMs via mfma_f32_16x16x32_bf16 with 3-product hi/lo splitting feed
// from LDS. Epilogue residual read also comes from the staged tap1 tile.
// ---------------------------------------------------------------------------
__global__ __launch_bounds__(256) void wn_block(
    const unsigned short* __restrict__ Xh, const unsigned short* __restrict__ Xl,
    unsigned short* __restrict__ Yh, unsigned short* __restrict__ Yl,
    const unsigned short* __restrict__ Wdh, const unsigned short* __restrict__ Wdl,
    const unsigned short* __restrict__ Wrh, const unsigned short* __restrict__ Wrl,
    const unsigned short* __restrict__ Wsh, const unsigned short* __restrict__ Wsl,
    const float* __restrict__ br, const float* __restrict__ bs,
    float* __restrict__ skip, int d, int col0)
{
    __shared__ char lds[LDS_BYTES];

    const int b     = blockIdx.y;
    const int tile0 = col0 + blockIdx.x * 32;
    const int tid   = threadIdx.x;
    const int lane  = tid & 63;
    const int wave  = tid >> 6;
    const int m0    = wave * 32;
    const int l15   = lane & 15, lq = lane >> 4;
    const size_t xbase = (size_t)b * TFULL * RC;

    // ---- stage X: wave w stages tensor w (hl = w>>1, tap = w&1).
    // Per q: lanes cover 4 cols x 16 chunks of 16B (one col row = 256 B).
    {
        const int hl  = wave >> 1, tap = wave & 1;
        const unsigned short* src = hl ? Xl : Xh;
        const int cshift = tap ? 0 : d;
        const int colq0 = lane >> 4;      // 0..3
        const int chunk = lane & 15;      // 0..15
        float4 v[8];
#pragma unroll
        for (int q = 0; q < 8; ++q) {
            int colq = q * 4 + colq0;
            int cg = tile0 + colq;
            cg = cg > TFULL - 1 ? TFULL - 1 : cg;   // tail clamp (masked at store)
            cg -= cshift;
            v[q] = *(const float4*)(src + xbase + (size_t)cg * RC + chunk * 8);
        }
        char* dstb = lds + (hl * 2 + tap) * TSZ + chunk * 16;
#pragma unroll
        for (int q = 0; q < 8; ++q)
            *(float4*)(dstb + (q * 4 + colq0) * COLPITCH) = v[q];
    }
    __syncthreads();

    // ---- dilated conv GEMM: K = 256 (k = tap*128 + ch), 3-product split
    f32x4 acc[2][2];
#pragma unroll
    for (int mf = 0; mf < 2; ++mf)
#pragma unroll
        for (int nf = 0; nf < 2; ++nf) acc[mf][nf] = (f32x4){0.f, 0.f, 0.f, 0.f};

#pragma unroll
    for (int ks = 0; ks < 8; ++ks) {
        const int tap = ks >> 2;
        const int kk  = ks & 3;
        bf16x8 ah[2], al[2];
#pragma unroll
        for (int mf = 0; mf < 2; ++mf) {
            size_t wi = ((size_t)(ks * 8 + wave * 2 + mf) * 64 + lane) * 8;
            ah[mf] = *(const bf16x8*)(Wdh + wi);
            al[mf] = *(const bf16x8*)(Wdl + wi);
        }
        bf16x8 bh[2], bl[2];
#pragma unroll
        for (int nf = 0; nf < 2; ++nf) {
            const char* pb = lds + tap * TSZ + (nf * 16 + l15) * COLPITCH + kk * 64 + lq * 16;
            bh[nf] = *(const bf16x8*)pb;
            bl[nf] = *(const bf16x8*)(pb + 2 * TSZ);
        }
#pragma unroll
        for (int mf = 0; mf < 2; ++mf)
#pragma unroll
            for (int nf = 0; nf < 2; ++nf) {
                acc[mf][nf] = __builtin_amdgcn_mfma_f32_16x16x32_bf16(ah[mf], bh[nf], acc[mf][nf], 0, 0, 0);
                acc[mf][nf] = __builtin_amdgcn_mfma_f32_16x16x32_bf16(ah[mf], bl[nf], acc[mf][nf], 0, 0, 0);
                acc[mf][nf] = __builtin_amdgcn_mfma_f32_16x16x32_bf16(al[mf], bh[nf], acc[mf][nf], 0, 0, 0);
            }
    }

    // ---- gate + write gated hi/lo to padded LDS [col][ch]
#pragma unroll
    for (int mf = 0; mf < 2; ++mf)
#pragma unroll
        for (int nf = 0; nf < 2; ++nf) {
            const int n   = nf * 16 + l15;
            const int ch0 = m0 + mf * 16 + lq * 4;
            char* pg = lds + GATED_BASE + n * COLPITCH + ch0 * 2;
            bf16x4 hv, lv;
#pragma unroll
            for (int r = 0; r < 4; ++r) {
                float y = acc[mf][nf][r];
                float g = tanhf(y) * (1.f / (1.f + expf(-y)));
                unsigned short h = f2bf(g);
                hv[r] = (short)h;
                lv[r] = (short)f2bf(g - bf2f(h));
            }
            *(bf16x4*)pg = hv;
            *(bf16x4*)(pg + TSZ) = lv;
        }
    __syncthreads();

    // ---- res & skip 1x1 GEMMs: K = 128 over gated
    f32x4 accr[2][2], accs[2][2];
#pragma unroll
    for (int mf = 0; mf < 2; ++mf)
#pragma unroll
        for (int nf = 0; nf < 2; ++nf) {
            accr[mf][nf] = (f32x4){0.f, 0.f, 0.f, 0.f};
            accs[mf][nf] = (f32x4){0.f, 0.f, 0.f, 0.f};
        }
#pragma unroll
    for (int ks = 0; ks < 4; ++ks) {
        bf16x8 rh[2], rl[2], sh[2], sl[2];
#pragma unroll
        for (int mf = 0; mf < 2; ++mf) {
            size_t wi = ((size_t)(ks * 8 + wave * 2 + mf) * 64 + lane) * 8;
            rh[mf] = *(const bf16x8*)(Wrh + wi);
            rl[mf] = *(const bf16x8*)(Wrl + wi);
            sh[mf] = *(const bf16x8*)(Wsh + wi);
            sl[mf] = *(const bf16x8*)(Wsl + wi);
        }
        bf16x8 gh[2], gl2[2];
#pragma unroll
        for (int nf = 0; nf < 2; ++nf) {
            const char* pg = lds + GATED_BASE + (nf * 16 + l15) * COLPITCH + ks * 64 + lq * 16;
            gh[nf]  = *(const bf16x8*)pg;
            gl2[nf] = *(const bf16x8*)(pg + TSZ);
        }
#pragma unroll
        for (int mf = 0; mf < 2; ++mf)
#pragma unroll
            for (int nf = 0; nf < 2; ++nf) {
                accr[mf][nf] = __builtin_amdgcn_mfma_f32_16x16x32_bf16(rh[mf], gh[nf],  accr[mf][nf], 0, 0, 0);
                accr[mf][nf] = __builtin_amdgcn_mfma_f32_16x16x32_bf16(rh[mf], gl2[nf], accr[mf][nf], 0, 0, 0);
                accr[mf][nf] = __builtin_amdgcn_mfma_f32_16x16x32_bf16(rl[mf], gh[nf],  accr[mf][nf], 0, 0, 0);
                accs[mf][nf] = __builtin_amdgcn_mfma_f32_16x16x32_bf16(sh[mf], gh[nf],  accs[mf][nf], 0, 0, 0);
                accs[mf][nf] = __builtin_amdgcn_mfma_f32_16x16x32_bf16(sh[mf], gl2[nf], accs[mf][nf], 0, 0, 0);
                accs[mf][nf] = __builtin_amdgcn_mfma_f32_16x16x32_bf16(sl[mf], gh[nf],  accs[mf][nf], 0, 0, 0);
            }
    }

    // ---- epilogue: residual add (fp32, input from staged tap1), re-split, store
    const int nt = TFULL - tile0 < 32 ? TFULL - tile0 : 32;
#pragma unroll
    for (int mf = 0; mf < 2; ++mf)
#pragma unroll
        for (int nf = 0; nf < 2; ++nf) {
            const int n   = nf * 16 + l15;
            const int c   = tile0 + n;
            const int ch0 = m0 + mf * 16 + lq * 4;
            const char* pr = lds + 1 * TSZ + n * COLPITCH + ch0 * 2;   // hi-tap1
            bf16x4 ih = *(const bf16x4*)pr;
            bf16x4 il = *(const bf16x4*)(pr + 2 * TSZ);                // lo-tap1
            const float4 brv = *(const float4*)(br + ch0);
            const float4 bsv = *(const float4*)(bs + ch0);
            bf16x4 oh, ol;
            float sk[4];
#pragma unroll
            for (int r = 0; r < 4; ++r) {
                float inv = bf2f((unsigned short)ih[r]) + bf2f((unsigned short)il[r]);
                float rv = accr[mf][nf][r] + ((const float*)&brv)[r] + inv;
                unsigned short h = f2bf(rv);
                oh[r] = (short)h;
                ol[r] = (short)f2bf(rv - bf2f(h));
                sk[r] = accs[mf][nf][r] + ((const float*)&bsv)[r];
            }
            if (n < nt) {
                const size_t off = xbase + (size_t)c * RC + ch0;
                *(bf16x4*)(Yh + off) = oh;
                *(bf16x4*)(Yl + off) = ol;
                if (c >= TFULL - SKIP_SZ) {
                    float* sp = skip + ((size_t)b * RC + ch0) * SKIP_SZ + (c - (TFULL - SKIP_SZ));
#pragma unroll
                    for (int r = 0; r < 4; ++r) sp[(size_t)r * SKIP_SZ] = sk[r];
                }
            }
        }
}

extern "C" void kernel_launch(void* const* d_in, const int* in_sizes, int n_in,
                              void* d_out, int out_size, void* d_ws, size_t ws_size,
                              hipStream_t stream) {
    const float* x  = (const float*)d_in[0];
    const float* Wd = (const float*)d_in[1];
    const float* Wr = (const float*)d_in[2];
    const float* br = (const float*)d_in[3];
    const float* Ws = (const float*)d_in[4];
    const float* bs = (const float*)d_in[5];
    float* out = (float*)d_out;

    // ws layout (u16 elems): 4 stream slots, then packed weights hi/lo
    const size_t SLOT = (size_t)BATCH * TFULL * RC;
    unsigned short* Xs0h = (unsigned short*)d_ws;
    unsigned short* Xs0l = Xs0h + SLOT;
    unsigned short* Xs1h = Xs0l + SLOT;
    unsigned short* Xs1l = Xs1h + SLOT;
    unsigned short* Wdh = Xs1l + SLOT;
    unsigned short* Wdl = Wdh + (size_t)NB * 32768;
    unsigned short* Wrh = Wdl + (size_t)NB * 32768;
    unsigned short* Wrl = Wrh + (size_t)NB * 16384;
    unsigned short* Wsh = Wrl + (size_t)NB * 16384;
    unsigned short* Wsl = Wsh + (size_t)NB * 16384;

    xpose_split<<<dim3(TFULL / 64, RC / 32, BATCH), 256, 0, stream>>>(x, Xs0h, Xs0l);
    {
        int total = NB * 4096 + 2 * NB * 2048;
        wpack<<<dim3((total + 255) / 256), 256, 0, stream>>>(Wd, Wr, Ws, Wdh, Wdl, Wrh, Wrl, Wsh, Wsl);
    }

    int L = TFULL;
    int pp = 0;
    for (int i = 0; i < NB; ++i) {
        const int d = 1 << (i % 10);
        const int Lout = L - d;
        const int col0 = TFULL - Lout;
        const int tiles = (Lout + 31) / 32;
        unsigned short* curh = pp ? Xs1h : Xs0h;
        unsigned short* curl = pp ? Xs1l : Xs0l;
        unsigned short* nxth = pp ? Xs0h : Xs1h;
        unsigned short* nxtl = pp ? Xs0l : Xs1l;
        wn_block<<<dim3(tiles, BATCH), 256, 0, stream>>>(
            curh, curl, nxth, nxtl,
            Wdh + (size_t)i * 32768, Wdl + (size_t)i * 32768,
            Wrh + (size_t)i * 16384, Wrl + (size_t)i * 16384,
            Wsh + (size_t)i * 16384, Wsl + (size_t)i * 16384,
            br + (size_t)i * RC, bs + (size_t)i * RC,
            out + (size_t)i * BATCH * RC * SKIP_SZ, d, col0);
        pp ^= 1;
        L = Lout;
    }
}